// Round 16
// baseline (119.217 us; speedup 1.0000x reference)
//
#include <hip/hip_runtime.h>
#include <hip/hip_cooperative_groups.h>
namespace cg = cooperative_groups;

#define BB   2
#define TT   2048
#define DIN  128
#define NS   64
#define CL   16
#define NC   128     // TT/CL
#define NSUP 16
#define SUPW 8       // NC/NSUP
#define NP   32      // NS/2 packed n-pairs
#define L2E  1.4426950408889634f

typedef float f2_t __attribute__((ext_vector_type(2)));
typedef float f4_t __attribute__((ext_vector_type(4)));

#if __has_builtin(__builtin_amdgcn_exp2f)
__device__ __forceinline__ float fexp2(float x) { return __builtin_amdgcn_exp2f(x); }
#else
__device__ __forceinline__ float fexp2(float x) { return exp2f(x); }
#endif

__device__ __forceinline__ unsigned int f2bfu(float f) {
  unsigned int u = __float_as_uint(f);
  u += 0x7FFFu + ((u >> 16) & 1u);
  return u >> 16;
}
__device__ __forceinline__ unsigned int packbf2(float a, float b) {
  return f2bfu(a) | (f2bfu(b) << 16);
}
__device__ __forceinline__ float bflo(unsigned int u) { return __uint_as_float(u << 16); }
__device__ __forceinline__ float bfhi(unsigned int u) { return __uint_as_float(u & 0xFFFF0000u); }

// ---- K1: xp = x @ W^T ; split into xcin / delta(sigmoid) / B / C ; a2 ----
__global__ __launch_bounds__(128) void k_proj(
    const float* __restrict__ x, const float* __restrict__ W,
    const float* __restrict__ A,
    float* __restrict__ xcin, float* __restrict__ delta,
    float* __restrict__ Bb, float* __restrict__ Cb, float* __restrict__ a2g) {
  __shared__ float xs[128 * 65];
  int tile = blockIdx.x, rg = blockIdx.y, tid = threadIdx.x;
  int base = tile * 128;
  const float4* __restrict__ x4 = (const float4*)(x + (size_t)base * 64);
  for (int i = tid; i < 128 * 16; i += 128) {
    float4 v = x4[i];
    int row = i >> 4, c4 = (i & 15) << 2;
    xs[row * 65 + c4 + 0] = v.x;
    xs[row * 65 + c4 + 1] = v.y;
    xs[row * 65 + c4 + 2] = v.z;
    xs[row * 65 + c4 + 3] = v.w;
  }
  if (tile == 0 && rg == 0 && tid < NS) {
    float s = 0.f;
    for (int m = 0; m < NS; ++m) s += A[tid * NS + m];
    a2g[tid] = s * L2E;
  }
  __syncthreads();
  float xr[64];
#pragma unroll
  for (int k = 0; k < 64; ++k) xr[k] = xs[tid * 65 + k];
  int bt = base + tid;
#pragma unroll 4
  for (int rr = 0; rr < 16; ++rr) {
    int r = rg * 16 + rr;
    const float* __restrict__ wrow = W + r * 64;
    float a0 = 0.f, a1 = 0.f, a2 = 0.f, a3 = 0.f;
#pragma unroll
    for (int k = 0; k < 64; k += 4) {
      a0 = fmaf(xr[k + 0], wrow[k + 0], a0);
      a1 = fmaf(xr[k + 1], wrow[k + 1], a1);
      a2 = fmaf(xr[k + 2], wrow[k + 2], a2);
      a3 = fmaf(xr[k + 3], wrow[k + 3], a3);
    }
    float acc = (a0 + a1) + (a2 + a3);
    if (r < 128) {
      xcin[(size_t)bt * DIN + r] = acc;
    } else if (r < 256) {
      delta[(size_t)bt * DIN + (r - 128)] = 1.f / (1.f + fexp2(-acc * L2E));
    } else if (r < 320) {
      Bb[(size_t)bt * NS + (r - 256)] = acc;
    } else {
      Cb[(size_t)bt * NS + (r - 320)] = acc;
    }
  }
}

// ---- K2: single cooperative kernel: scan1 -> comb -> scan2 (2 grid syncs) ----
__global__ __launch_bounds__(1024) void k_main(
    const float* __restrict__ xcin, const float* __restrict__ delta,
    const float* __restrict__ Bb, const float* __restrict__ Cb,
    const float* __restrict__ a2g, const float* __restrict__ cw,
    const float* __restrict__ cb, const float* __restrict__ Dp,
    unsigned int* __restrict__ hendP, float* __restrict__ sumd,
    unsigned int* __restrict__ hinP, float* __restrict__ out) {
  // phase-1 staging
  __shared__ float xcs[(CL + 3) * DIN];  // 9.5 KB
  __shared__ float des[CL * DIN];        // 8 KB
  __shared__ float Bs[CL * NS];          // 4 KB
  // phase-2
  __shared__ float S0[NSUP][64], S1[NSUP][64], sdS[NSUP][64];  // 12 KB
  __shared__ float C0[NSUP][64], C1[NSUP][64];                 // 8 KB
  // phase-3
  __shared__ float yred[8][CL][DIN];     // 64 KB
  cg::grid_group grid = cg::this_grid();
  const int bid = blockIdx.x, tid = threadIdx.x;
  const int d = tid & 127;

  float cw0 = cw[d * 4 + 0], cw1 = cw[d * 4 + 1], cw2 = cw[d * 4 + 2], cw3 = cw[d * 4 + 3];
  float cbd = cb[d];
  float Dd = Dp[d];

  // ================= PHASE 1: merged fwd+rev local chunk scans =================
  {
    int c = bid & 127, b = bid >> 7;
    int g = __builtin_amdgcn_readfirstlane(tid >> 7);  // 8 n-groups of 8
    int t0 = c * CL;
    {
      const float* __restrict__ xcB = xcin + (size_t)b * TT * DIN;
      for (int i = tid; i < (CL + 3) * 32; i += 1024) {
        int row = i >> 5, c4 = i & 31;
        int t = t0 - 3 + row;
        float4 v = make_float4(0.f, 0.f, 0.f, 0.f);
        if (t >= 0) v = ((const float4*)(xcB + (size_t)t * DIN))[c4];
        ((float4*)xcs)[i] = v;
      }
      if (tid < CL * 32)
        ((float4*)des)[tid] = ((const float4*)(delta + (size_t)(b * TT + t0) * DIN))[tid];
      if (tid < CL * 16)
        ((float4*)Bs)[tid] = ((const float4*)(Bb + (size_t)(b * TT + t0) * NS))[tid];
    }
    int nb = g * 8;
    f2_t a2p[4];
#pragma unroll
    for (int j = 0; j < 4; ++j) { a2p[j].x = a2g[nb + 2 * j]; a2p[j].y = a2g[nb + 2 * j + 1]; }
    __syncthreads();
    f2_t hf[4], hr[4], Pp[4];
#pragma unroll
    for (int j = 0; j < 4; ++j) {
      hf[j] = (f2_t){0.f, 0.f}; hr[j] = (f2_t){0.f, 0.f}; Pp[j] = (f2_t){1.f, 1.f};
    }
    float sd = 0.f;
    float w0 = xcs[0 * DIN + d], w1 = xcs[1 * DIN + d], w2 = xcs[2 * DIN + d];
#pragma unroll
    for (int i = 0; i < CL; ++i) {
      float w3 = xcs[(i + 3) * DIN + d];
      float xconv = fmaf(cw0, w0, fmaf(cw1, w1, fmaf(cw2, w2, fmaf(cw3, w3, cbd))));
      float de = des[i * DIN + d];
      sd += de;
      float dxv = de * xconv;
      const f2_t* __restrict__ B2 = (const f2_t*)&Bs[i * NS + nb];
#pragma unroll
      for (int j = 0; j < 4; ++j) {
        f2_t b2 = dxv * B2[j];
        f2_t e2;
        e2.x = fexp2(de * a2p[j].x);
        e2.y = fexp2(de * a2p[j].y);
        hf[j] = e2 * hf[j] + b2;
        hr[j] = Pp[j] * b2 + hr[j];
        Pp[j] = Pp[j] * e2;
      }
      w0 = w1; w1 = w2; w2 = w3;
    }
    size_t h0 = (((size_t)(0 * NC + c) * BB + b) * NP + (nb >> 1)) * DIN + d;
    size_t h1 = (((size_t)(1 * NC + c) * BB + b) * NP + (nb >> 1)) * DIN + d;
#pragma unroll
    for (int j = 0; j < 4; ++j) {
      hendP[h0 + (size_t)j * DIN] = packbf2(hf[j].x, hf[j].y);
      hendP[h1 + (size_t)j * DIN] = packbf2(hr[j].x, hr[j].y);
    }
    if (g == 0) sumd[(c * BB + b) * DIN + d] = sd;
  }
  grid.sync();

  // ================= PHASE 2: fused combine -> hinP =================
  {
    int dh = bid & 1;
    int np = (bid >> 1) & 31;
    int dir = (bid >> 6) & 1;
    int b = bid >> 7;
    int dl = tid & 63;
    int dd = dh * 64 + dl;
    int sp = __builtin_amdgcn_readfirstlane(tid >> 6);   // 0..15 = super id
    float a2n0 = a2g[2 * np], a2n1 = a2g[2 * np + 1];
    float hinLo0[SUPW], hinLo1[SUPW], pfLoc[SUPW];
    float c0 = 0.f, c1 = 0.f, pf = 0.f;
#pragma unroll
    for (int k = 0; k < SUPW; ++k) {
      int cc = sp * SUPW + (dir ? (SUPW - 1 - k) : k);
      float sdv = sumd[(cc * BB + b) * DIN + dd];
      unsigned int hv = hendP[(((size_t)(dir * NC + cc) * BB + b) * NP + np) * DIN + dd];
      hinLo0[k] = c0; hinLo1[k] = c1; pfLoc[k] = pf;
      float e0 = fexp2(a2n0 * sdv);
      float e1 = fexp2(a2n1 * sdv);
      c0 = fmaf(e0, c0, bflo(hv));
      c1 = fmaf(e1, c1, bfhi(hv));
      pf += sdv;
    }
    S0[sp][dl] = c0; S1[sp][dl] = c1; sdS[sp][dl] = pf;
    __syncthreads();
    if (sp == 0) {
      float g0 = 0.f, g1 = 0.f;
#pragma unroll
      for (int k = 0; k < NSUP; ++k) {
        int spp = dir ? (NSUP - 1 - k) : k;
        C0[spp][dl] = g0; C1[spp][dl] = g1;
        float sv = sdS[spp][dl];
        float e0 = fexp2(a2n0 * sv);
        float e1 = fexp2(a2n1 * sv);
        g0 = fmaf(e0, g0, S0[spp][dl]);
        g1 = fmaf(e1, g1, S1[spp][dl]);
      }
    }
    __syncthreads();
    float cs0 = C0[sp][dl], cs1 = C1[sp][dl];
#pragma unroll
    for (int k = 0; k < SUPW; ++k) {
      int cc = sp * SUPW + (dir ? (SUPW - 1 - k) : k);
      float pe0 = fexp2(a2n0 * pfLoc[k]);
      float pe1 = fexp2(a2n1 * pfLoc[k]);
      float v0 = fmaf(pe0, cs0, hinLo0[k]);
      float v1 = fmaf(pe1, cs1, hinLo1[k]);
      hinP[(((size_t)(dir * NC + cc) * BB + b) * NP + np) * DIN + dd] = packbf2(v0, v1);
    }
  }
  grid.sync();

  // ================= PHASE 3: both-dir full scans; LDS reduce; store =================
  {
    int c = bid & 127, b = bid >> 7;
    int g = __builtin_amdgcn_readfirstlane(tid >> 7);  // 0..7
    int dir = g >> 2;                                  // groups 0-3 fwd, 4-7 rev
    int nb = (g & 3) * 16;
    f2_t a2p[8];
#pragma unroll
    for (int j = 0; j < 8; ++j) { a2p[j].x = a2g[nb + 2 * j]; a2p[j].y = a2g[nb + 2 * j + 1]; }
    f2_t h2[8];
    size_t hb0 = (((size_t)(dir * NC + c) * BB + b) * NP + (nb >> 1)) * DIN + d;
#pragma unroll
    for (int jp = 0; jp < 8; ++jp) {
      unsigned int u = hinP[hb0 + (size_t)jp * DIN];
      h2[jp].x = bflo(u);
      h2[jp].y = bfhi(u);
    }
    int t0 = c * CL;
    const float* __restrict__ xcB = xcin + (size_t)b * TT * DIN + d;
    const float* __restrict__ deB = delta + (size_t)b * TT * DIN + d;
    const float* __restrict__ BbB = Bb + (size_t)b * TT * NS + nb;
    const float* __restrict__ CbB = Cb + (size_t)b * TT * NS + nb;
    bool addD = (g == 0);
    float w0, w1, w2, w3;
    if (dir == 0) {
      int t = t0;
      w0 = (t - 3 >= 0) ? xcB[(t - 3) * DIN] : 0.f;
      w1 = (t - 2 >= 0) ? xcB[(t - 2) * DIN] : 0.f;
      w2 = (t - 1 >= 0) ? xcB[(t - 1) * DIN] : 0.f;
      w3 = xcB[t * DIN];
#pragma unroll
      for (int i = 0; i < CL; ++i) {
        float xconv = fmaf(cw0, w0, fmaf(cw1, w1, fmaf(cw2, w2, fmaf(cw3, w3, cbd))));
        float de = deB[t * DIN];
        float dxv = de * xconv;
        f2_t y2 = (f2_t){0.f, 0.f};
#pragma unroll
        for (int jq = 0; jq < 4; ++jq) {
          f4_t bq = *(const f4_t*)&BbB[t * NS + jq * 4];
          f4_t cq = *(const f4_t*)&CbB[t * NS + jq * 4];
          f2_t blo = __builtin_shufflevector(bq, bq, 0, 1);
          f2_t bhi = __builtin_shufflevector(bq, bq, 2, 3);
          f2_t clo = __builtin_shufflevector(cq, cq, 0, 1);
          f2_t chi = __builtin_shufflevector(cq, cq, 2, 3);
          int jp = 2 * jq;
          f2_t e2;
          e2.x = fexp2(de * a2p[jp].x);
          e2.y = fexp2(de * a2p[jp].y);
          h2[jp] = e2 * h2[jp] + dxv * blo;
          y2 = h2[jp] * clo + y2;
          f2_t e3;
          e3.x = fexp2(de * a2p[jp + 1].x);
          e3.y = fexp2(de * a2p[jp + 1].y);
          h2[jp + 1] = e3 * h2[jp + 1] + dxv * bhi;
          y2 = h2[jp + 1] * chi + y2;
        }
        float yv = y2.x + y2.y;
        if (addD) yv = fmaf(Dd, xconv, yv);
        yred[g][i][d] = yv;
        if (i < CL - 1) { ++t; w0 = w1; w1 = w2; w2 = w3; w3 = xcB[t * DIN]; }
      }
    } else {
      int t = t0 + CL - 1;
      w3 = xcB[t * DIN];
      w2 = xcB[(t - 1) * DIN];
      w1 = xcB[(t - 2) * DIN];
      w0 = xcB[(t - 3) * DIN];
#pragma unroll
      for (int i = 0; i < CL; ++i) {
        float xconv = fmaf(cw0, w0, fmaf(cw1, w1, fmaf(cw2, w2, fmaf(cw3, w3, cbd))));
        float de = deB[t * DIN];
        float dxv = de * xconv;
        f2_t y2 = (f2_t){0.f, 0.f};
#pragma unroll
        for (int jq = 0; jq < 4; ++jq) {
          f4_t bq = *(const f4_t*)&BbB[t * NS + jq * 4];
          f4_t cq = *(const f4_t*)&CbB[t * NS + jq * 4];
          f2_t blo = __builtin_shufflevector(bq, bq, 0, 1);
          f2_t bhi = __builtin_shufflevector(bq, bq, 2, 3);
          f2_t clo = __builtin_shufflevector(cq, cq, 0, 1);
          f2_t chi = __builtin_shufflevector(cq, cq, 2, 3);
          int jp = 2 * jq;
          f2_t e2;
          e2.x = fexp2(de * a2p[jp].x);
          e2.y = fexp2(de * a2p[jp].y);
          h2[jp] = e2 * h2[jp] + dxv * blo;
          y2 = h2[jp] * clo + y2;
          f2_t e3;
          e3.x = fexp2(de * a2p[jp + 1].x);
          e3.y = fexp2(de * a2p[jp + 1].y);
          h2[jp + 1] = e3 * h2[jp + 1] + dxv * bhi;
          y2 = h2[jp + 1] * chi + y2;
        }
        float yv = y2.x + y2.y;
        yred[g][i][d] = yv;
        if (i < CL - 1) { --t; w3 = w2; w2 = w1; w1 = w0; w0 = (t - 3 >= 0) ? xcB[(t - 3) * DIN] : 0.f; }
      }
    }
    __syncthreads();
#pragma unroll
    for (int k = 0; k < 2; ++k) {
      int p = k * 1024 + tid;
      int i = p >> 7, d2 = p & 127;
      int ir = CL - 1 - i;
      float sf = (yred[0][i][d2] + yred[1][i][d2]) + (yred[2][i][d2] + yred[3][i][d2]);
      float sr = (yred[4][ir][d2] + yred[5][ir][d2]) + (yred[6][ir][d2] + yred[7][ir][d2]);
      out[((size_t)b * TT + t0 + i) * DIN + d2] = sf + sr;
    }
  }
}

extern "C" void kernel_launch(void* const* d_in, const int* in_sizes, int n_in,
                              void* d_out, int out_size, void* d_ws, size_t ws_size,
                              hipStream_t stream) {
  const float* x  = (const float*)d_in[0];
  const float* W  = (const float*)d_in[1];
  const float* cw = (const float*)d_in[2];
  const float* cb = (const float*)d_in[3];
  const float* A  = (const float*)d_in[4];
  const float* Dp = (const float*)d_in[5];
  float* out = (float*)d_out;

  float* ws = (float*)d_ws;
  float* xcin   = ws;                      // 524288
  float* delta  = xcin + 524288;           // 524288
  float* Bbuf   = delta + 524288;          // 262144
  float* Cbuf   = Bbuf + 262144;           // 262144
  float* a2g    = Cbuf + 262144;           // 128
  float* sumd   = a2g + 128;               // 32768
  unsigned int* hendP = (unsigned int*)(sumd + 32768);   // 2097152 uints
  unsigned int* hinP  = hendP + 2097152;                 // 2097152 uints
  // total ~23 MB

  hipLaunchKernelGGL(k_proj, dim3(32, 24), dim3(128), 0, stream,
                     x, W, A, xcin, delta, Bbuf, Cbuf, a2g);

  void* kargs[] = {
    (void*)&xcin, (void*)&delta, (void*)&Bbuf, (void*)&Cbuf, (void*)&a2g,
    (void*)&cw, (void*)&cb, (void*)&Dp,
    (void*)&hendP, (void*)&sumd, (void*)&hinP, (void*)&out
  };
  hipLaunchCooperativeKernel((void*)k_main, dim3(256), dim3(1024), kargs, 0, stream);
}

// Round 17
// 85.484 us; speedup vs baseline: 1.3946x; 1.3946x over previous
//
#include <hip/hip_runtime.h>

#define BB   2
#define TT   2048
#define DIN  128
#define NS   64
#define CL   16
#define NC   128     // TT/CL
#define NSUP 16
#define SUPW 8       // NC/NSUP
#define NP   32      // NS/2 packed n-pairs
#define L2E  1.4426950408889634f

typedef float f2_t __attribute__((ext_vector_type(2)));
typedef float f4_t __attribute__((ext_vector_type(4)));

#if __has_builtin(__builtin_amdgcn_exp2f)
__device__ __forceinline__ float fexp2(float x) { return __builtin_amdgcn_exp2f(x); }
#else
__device__ __forceinline__ float fexp2(float x) { return exp2f(x); }
#endif

__device__ __forceinline__ unsigned int f2bfu(float f) {
  unsigned int u = __float_as_uint(f);
  u += 0x7FFFu + ((u >> 16) & 1u);
  return u >> 16;
}
__device__ __forceinline__ unsigned int packbf2(float a, float b) {
  return f2bfu(a) | (f2bfu(b) << 16);
}
__device__ __forceinline__ float bflo(unsigned int u) { return __uint_as_float(u << 16); }
__device__ __forceinline__ float bfhi(unsigned int u) { return __uint_as_float(u & 0xFFFF0000u); }

// ---- K1: fused proj+scan1: in-block projection (19 halo rows) -> LDS,
//      write xcin/delta/B/C for scan2, then merged fwd+rev chunk scan ----
__global__ __launch_bounds__(1024) void k_scan1p(
    const float* __restrict__ x, const float* __restrict__ W,
    const float* __restrict__ A,
    const float* __restrict__ cw, const float* __restrict__ cb,
    float* __restrict__ xcin, float* __restrict__ delta,
    float* __restrict__ Bb, float* __restrict__ Cb,
    unsigned int* __restrict__ hendP, float* __restrict__ sumd) {
  __shared__ float xs[19 * 64];          // 4.75 KB staged x rows t0-3..t0+15
  __shared__ float a2s[NS];              // 0.25 KB
  __shared__ float xcs[(CL + 3) * DIN];  // 9.5 KB
  __shared__ float des[CL * DIN];        // 8 KB
  __shared__ float Bs[CL * NS];          // 4 KB
  __shared__ float Cs[CL * NS];          // 4 KB
  int c = blockIdx.x, b = blockIdx.y;
  int tid = threadIdx.x;
  int d = tid & 127;
  int g = __builtin_amdgcn_readfirstlane(tid >> 7);  // 8 n-groups of 8
  int t0 = c * CL;
  // stage x rows (halo-inclusive) and a2
  for (int i = tid; i < 19 * 16; i += 1024) {
    int row = i >> 4;
    int t = t0 - 3 + row;
    float4 v = make_float4(0.f, 0.f, 0.f, 0.f);
    if (t >= 0) v = ((const float4*)(x + ((size_t)b * TT + t) * 64))[i & 15];
    ((float4*)xs)[i] = v;
  }
  if (tid < NS) {
    float s = 0.f;
    const float* __restrict__ Ar = A + tid * NS;
#pragma unroll 8
    for (int m = 0; m < NS; ++m) s += Ar[m];
    a2s[tid] = s * L2E;
  }
  __syncthreads();
  // in-block projection: 6528 dot-64 tasks
  for (int i = tid; i < 6528; i += 1024) {
    int kind, row, col, wr;
    if (i < 2432)      { kind = 0; row = i >> 7;            col = i & 127; wr = col; }
    else if (i < 4480) { kind = 1; row = (i - 2432) >> 7;   col = (i - 2432) & 127; wr = 128 + col; }
    else if (i < 5504) { kind = 2; row = (i - 4480) >> 6;   col = (i - 4480) & 63;  wr = 256 + col; }
    else               { kind = 3; row = (i - 5504) >> 6;   col = (i - 5504) & 63;  wr = 320 + col; }
    int xrow = (kind == 0) ? row : (row + 3);
    const float4* __restrict__ w4 = (const float4*)(W + wr * 64);
    const float4* __restrict__ x4r = (const float4*)(xs + xrow * 64);
    float a0 = 0.f, a1 = 0.f, a2 = 0.f, a3 = 0.f;
#pragma unroll
    for (int k = 0; k < 16; ++k) {
      float4 wv = w4[k];
      float4 xv = x4r[k];
      a0 = fmaf(wv.x, xv.x, a0);
      a1 = fmaf(wv.y, xv.y, a1);
      a2 = fmaf(wv.z, xv.z, a2);
      a3 = fmaf(wv.w, xv.w, a3);
    }
    float acc = (a0 + a1) + (a2 + a3);
    if (kind == 0) {
      xcs[row * DIN + col] = acc;
      if (row >= 3) xcin[((size_t)b * TT + (t0 + row - 3)) * DIN + col] = acc;
    } else if (kind == 1) {
      float dv = 1.f / (1.f + fexp2(-acc * L2E));
      des[row * DIN + col] = dv;
      delta[((size_t)b * TT + (t0 + row)) * DIN + col] = dv;
    } else if (kind == 2) {
      Bs[row * NS + col] = acc;
      Bb[((size_t)b * TT + (t0 + row)) * NS + col] = acc;
    } else {
      Cs[row * NS + col] = acc;
      Cb[((size_t)b * TT + (t0 + row)) * NS + col] = acc;
    }
  }
  float cw0 = cw[d * 4 + 0], cw1 = cw[d * 4 + 1], cw2 = cw[d * 4 + 2], cw3 = cw[d * 4 + 3];
  float cbd = cb[d];
  int nb = g * 8;
  __syncthreads();
  f2_t a2p[4];
#pragma unroll
  for (int j = 0; j < 4; ++j) { a2p[j].x = a2s[nb + 2 * j]; a2p[j].y = a2s[nb + 2 * j + 1]; }
  f2_t hf[4], hr[4], Pp[4];
#pragma unroll
  for (int j = 0; j < 4; ++j) {
    hf[j] = (f2_t){0.f, 0.f}; hr[j] = (f2_t){0.f, 0.f}; Pp[j] = (f2_t){1.f, 1.f};
  }
  float sd = 0.f;
  float w0 = xcs[0 * DIN + d], w1 = xcs[1 * DIN + d], w2 = xcs[2 * DIN + d];
#pragma unroll
  for (int i = 0; i < CL; ++i) {
    float w3 = xcs[(i + 3) * DIN + d];
    float xconv = fmaf(cw0, w0, fmaf(cw1, w1, fmaf(cw2, w2, fmaf(cw3, w3, cbd))));
    float de = des[i * DIN + d];
    sd += de;
    float dxv = de * xconv;
    const f2_t* __restrict__ B2 = (const f2_t*)&Bs[i * NS + nb];
#pragma unroll
    for (int j = 0; j < 4; ++j) {
      f2_t b2 = dxv * B2[j];
      f2_t e2;
      e2.x = fexp2(de * a2p[j].x);
      e2.y = fexp2(de * a2p[j].y);
      hf[j] = e2 * hf[j] + b2;     // v_pk_fma_f32
      hr[j] = Pp[j] * b2 + hr[j];  // v_pk_fma_f32
      Pp[j] = Pp[j] * e2;          // v_pk_mul_f32
    }
    w0 = w1; w1 = w2; w2 = w3;
  }
  size_t h0 = (((size_t)(0 * NC + c) * BB + b) * NP + (nb >> 1)) * DIN + d;
  size_t h1 = (((size_t)(1 * NC + c) * BB + b) * NP + (nb >> 1)) * DIN + d;
#pragma unroll
  for (int j = 0; j < 4; ++j) {
    hendP[h0 + (size_t)j * DIN] = packbf2(hf[j].x, hf[j].y);
    hendP[h1 + (size_t)j * DIN] = packbf2(hr[j].x, hr[j].y);
  }
  if (g == 0) sumd[(c * BB + b) * DIN + d] = sd;
}

// ---- K2: fused combine (full-CU grid 256x512):
//      super chains (regs) + 16-super chain (LDS) + Csup fold -> hinP ----
__global__ __launch_bounds__(512) void k_comb(
    const unsigned int* __restrict__ hendP, const float* __restrict__ sumd,
    const float* __restrict__ A, unsigned int* __restrict__ hinP) {
  __shared__ float S0[NSUP][64], S1[NSUP][64];     // 8 KB
  __shared__ float sdS[NSUP][64];                  // 4 KB
  __shared__ float C0[NSUP][64], C1[NSUP][64];     // 8 KB
  __shared__ float sc2[2];
  int bid = blockIdx.x;            // 256 = (b, dir, np, dh)
  int dh = bid & 1;
  int np = (bid >> 1) & 31;
  int dir = (bid >> 6) & 1;
  int b = bid >> 7;
  int tid = threadIdx.x;
  int dl = tid & 63;
  int d = dh * 64 + dl;
  int sl = __builtin_amdgcn_readfirstlane(tid >> 6);   // 0..7
  if (tid < 2) {
    float s = 0.f;
    const float* __restrict__ Ar = A + (2 * np + tid) * NS;
#pragma unroll 8
    for (int m = 0; m < NS; ++m) s += Ar[m];
    sc2[tid] = s * L2E;
  }
  __syncthreads();
  float a2n0 = sc2[0], a2n1 = sc2[1];
  float hinLo0[2][SUPW], hinLo1[2][SUPW], pfLoc[2][SUPW];
#pragma unroll
  for (int ss = 0; ss < 2; ++ss) {
    int sp = sl + ss * 8;
    float c0 = 0.f, c1 = 0.f, pf = 0.f;
#pragma unroll
    for (int k = 0; k < SUPW; ++k) {
      int cc = sp * SUPW + (dir ? (SUPW - 1 - k) : k);
      float sdv = sumd[(cc * BB + b) * DIN + d];
      unsigned int hv = hendP[(((size_t)(dir * NC + cc) * BB + b) * NP + np) * DIN + d];
      hinLo0[ss][k] = c0; hinLo1[ss][k] = c1; pfLoc[ss][k] = pf;
      float e0 = fexp2(a2n0 * sdv);
      float e1 = fexp2(a2n1 * sdv);
      c0 = fmaf(e0, c0, bflo(hv));
      c1 = fmaf(e1, c1, bfhi(hv));
      pf += sdv;
    }
    S0[sp][dl] = c0; S1[sp][dl] = c1; sdS[sp][dl] = pf;
  }
  __syncthreads();
  if (sl == 0) {
    float c0 = 0.f, c1 = 0.f;
#pragma unroll
    for (int k = 0; k < NSUP; ++k) {
      int sp = dir ? (NSUP - 1 - k) : k;
      C0[sp][dl] = c0; C1[sp][dl] = c1;
      float sv = sdS[sp][dl];
      float e0 = fexp2(a2n0 * sv);
      float e1 = fexp2(a2n1 * sv);
      c0 = fmaf(e0, c0, S0[sp][dl]);
      c1 = fmaf(e1, c1, S1[sp][dl]);
    }
  }
  __syncthreads();
#pragma unroll
  for (int ss = 0; ss < 2; ++ss) {
    int sp = sl + ss * 8;
    float cs0 = C0[sp][dl], cs1 = C1[sp][dl];
#pragma unroll
    for (int k = 0; k < SUPW; ++k) {
      int cc = sp * SUPW + (dir ? (SUPW - 1 - k) : k);
      float pe0 = fexp2(a2n0 * pfLoc[ss][k]);
      float pe1 = fexp2(a2n1 * pfLoc[ss][k]);
      float v0 = fmaf(pe0, cs0, hinLo0[ss][k]);
      float v1 = fmaf(pe1, cs1, hinLo1[ss][k]);
      hinP[(((size_t)(dir * NC + cc) * BB + b) * NP + np) * DIN + d] = packbf2(v0, v1);
    }
  }
}

// ---- K3: both-direction full scans; init = hinP only; pk f32; LDS reduce ----
__global__ __launch_bounds__(1024) void k_scan2(
    const float* __restrict__ xcin, const float* __restrict__ delta,
    const float* __restrict__ Bb, const float* __restrict__ Cb,
    const float* __restrict__ A, const float* __restrict__ cw,
    const float* __restrict__ cb, const float* __restrict__ Dp,
    const unsigned int* __restrict__ hinP,
    float* __restrict__ out) {
  __shared__ float yred[8][CL][DIN];   // 64 KB
  __shared__ float a2s[NS];
  int c = blockIdx.x, b = blockIdx.y;
  int tid = threadIdx.x;
  int d = tid & 127;
  int g = __builtin_amdgcn_readfirstlane(tid >> 7);  // 0..7
  int dir = g >> 2;                                  // groups 0-3 fwd, 4-7 rev
  int nb = (g & 3) * 16;
  if (tid < NS) {
    float s = 0.f;
    const float* __restrict__ Ar = A + tid * NS;
#pragma unroll 8
    for (int m = 0; m < NS; ++m) s += Ar[m];
    a2s[tid] = s * L2E;
  }
  __syncthreads();
  float cw0 = cw[d * 4 + 0], cw1 = cw[d * 4 + 1], cw2 = cw[d * 4 + 2], cw3 = cw[d * 4 + 3];
  float cbd = cb[d];
  float Dd = Dp[d];
  f2_t a2p[8];
#pragma unroll
  for (int j = 0; j < 8; ++j) { a2p[j].x = a2s[nb + 2 * j]; a2p[j].y = a2s[nb + 2 * j + 1]; }
  f2_t h2[8];
  size_t hb0 = (((size_t)(dir * NC + c) * BB + b) * NP + (nb >> 1)) * DIN + d;
#pragma unroll
  for (int jp = 0; jp < 8; ++jp) {
    unsigned int u = hinP[hb0 + (size_t)jp * DIN];
    h2[jp].x = bflo(u);
    h2[jp].y = bfhi(u);
  }
  int t0 = c * CL;
  const float* __restrict__ xcB = xcin + (size_t)b * TT * DIN + d;
  const float* __restrict__ deB = delta + (size_t)b * TT * DIN + d;
  const float* __restrict__ BbB = Bb + (size_t)b * TT * NS + nb;
  const float* __restrict__ CbB = Cb + (size_t)b * TT * NS + nb;
  bool addD = (g == 0);
  float w0, w1, w2, w3;
  if (dir == 0) {
    int t = t0;
    w0 = (t - 3 >= 0) ? xcB[(t - 3) * DIN] : 0.f;
    w1 = (t - 2 >= 0) ? xcB[(t - 2) * DIN] : 0.f;
    w2 = (t - 1 >= 0) ? xcB[(t - 1) * DIN] : 0.f;
    w3 = xcB[t * DIN];
#pragma unroll
    for (int i = 0; i < CL; ++i) {
      float xconv = fmaf(cw0, w0, fmaf(cw1, w1, fmaf(cw2, w2, fmaf(cw3, w3, cbd))));
      float de = deB[t * DIN];
      float dxv = de * xconv;
      f2_t y2 = (f2_t){0.f, 0.f};
#pragma unroll
      for (int jq = 0; jq < 4; ++jq) {
        f4_t bq = *(const f4_t*)&BbB[t * NS + jq * 4];
        f4_t cq = *(const f4_t*)&CbB[t * NS + jq * 4];
        f2_t blo = __builtin_shufflevector(bq, bq, 0, 1);
        f2_t bhi = __builtin_shufflevector(bq, bq, 2, 3);
        f2_t clo = __builtin_shufflevector(cq, cq, 0, 1);
        f2_t chi = __builtin_shufflevector(cq, cq, 2, 3);
        int jp = 2 * jq;
        f2_t e2;
        e2.x = fexp2(de * a2p[jp].x);
        e2.y = fexp2(de * a2p[jp].y);
        h2[jp] = e2 * h2[jp] + dxv * blo;
        y2 = h2[jp] * clo + y2;
        f2_t e3;
        e3.x = fexp2(de * a2p[jp + 1].x);
        e3.y = fexp2(de * a2p[jp + 1].y);
        h2[jp + 1] = e3 * h2[jp + 1] + dxv * bhi;
        y2 = h2[jp + 1] * chi + y2;
      }
      float yv = y2.x + y2.y;
      if (addD) yv = fmaf(Dd, xconv, yv);
      yred[g][i][d] = yv;
      if (i < CL - 1) { ++t; w0 = w1; w1 = w2; w2 = w3; w3 = xcB[t * DIN]; }
    }
  } else {
    int t = t0 + CL - 1;
    w3 = xcB[t * DIN];
    w2 = xcB[(t - 1) * DIN];
    w1 = xcB[(t - 2) * DIN];
    w0 = xcB[(t - 3) * DIN];
#pragma unroll
    for (int i = 0; i < CL; ++i) {
      float xconv = fmaf(cw0, w0, fmaf(cw1, w1, fmaf(cw2, w2, fmaf(cw3, w3, cbd))));
      float de = deB[t * DIN];
      float dxv = de * xconv;
      f2_t y2 = (f2_t){0.f, 0.f};
#pragma unroll
      for (int jq = 0; jq < 4; ++jq) {
        f4_t bq = *(const f4_t*)&BbB[t * NS + jq * 4];
        f4_t cq = *(const f4_t*)&CbB[t * NS + jq * 4];
        f2_t blo = __builtin_shufflevector(bq, bq, 0, 1);
        f2_t bhi = __builtin_shufflevector(bq, bq, 2, 3);
        f2_t clo = __builtin_shufflevector(cq, cq, 0, 1);
        f2_t chi = __builtin_shufflevector(cq, cq, 2, 3);
        int jp = 2 * jq;
        f2_t e2;
        e2.x = fexp2(de * a2p[jp].x);
        e2.y = fexp2(de * a2p[jp].y);
        h2[jp] = e2 * h2[jp] + dxv * blo;
        y2 = h2[jp] * clo + y2;
        f2_t e3;
        e3.x = fexp2(de * a2p[jp + 1].x);
        e3.y = fexp2(de * a2p[jp + 1].y);
        h2[jp + 1] = e3 * h2[jp + 1] + dxv * bhi;
        y2 = h2[jp + 1] * chi + y2;
      }
      float yv = y2.x + y2.y;
      yred[g][i][d] = yv;
      if (i < CL - 1) { --t; w3 = w2; w2 = w1; w1 = w0; w0 = (t - 3 >= 0) ? xcB[(t - 3) * DIN] : 0.f; }
    }
  }
  __syncthreads();
#pragma unroll
  for (int k = 0; k < 2; ++k) {
    int p = k * 1024 + tid;
    int i = p >> 7, d2 = p & 127;
    int ir = CL - 1 - i;
    float sf = (yred[0][i][d2] + yred[1][i][d2]) + (yred[2][i][d2] + yred[3][i][d2]);
    float sr = (yred[4][ir][d2] + yred[5][ir][d2]) + (yred[6][ir][d2] + yred[7][ir][d2]);
    out[((size_t)b * TT + t0 + i) * DIN + d2] = sf + sr;
  }
}

extern "C" void kernel_launch(void* const* d_in, const int* in_sizes, int n_in,
                              void* d_out, int out_size, void* d_ws, size_t ws_size,
                              hipStream_t stream) {
  const float* x  = (const float*)d_in[0];
  const float* W  = (const float*)d_in[1];
  const float* cw = (const float*)d_in[2];
  const float* cb = (const float*)d_in[3];
  const float* A  = (const float*)d_in[4];
  const float* Dp = (const float*)d_in[5];
  float* out = (float*)d_out;

  float* ws = (float*)d_ws;
  float* xcin   = ws;                      // 524288
  float* delta  = xcin + 524288;           // 524288
  float* Bbuf   = delta + 524288;          // 262144
  float* Cbuf   = Bbuf + 262144;           // 262144
  float* sumd   = Cbuf + 262144;           // 32768
  unsigned int* hendP = (unsigned int*)(sumd + 32768);   // 2097152 uints
  unsigned int* hinP  = hendP + 2097152;                 // 2097152 uints
  // total ~23 MB

  hipLaunchKernelGGL(k_scan1p, dim3(NC, BB), dim3(1024), 0, stream,
                     x, W, A, cw, cb, xcin, delta, Bbuf, Cbuf, hendP, sumd);
  hipLaunchKernelGGL(k_comb,   dim3(256), dim3(512), 0, stream,
                     hendP, sumd, A, hinP);
  hipLaunchKernelGGL(k_scan2,  dim3(NC, BB), dim3(1024), 0, stream,
                     xcin, delta, Bbuf, Cbuf, A, cw, cb, Dp, hinP, out);
}

// Round 18
// 64.781 us; speedup vs baseline: 1.8403x; 1.3196x over previous
//
#include <hip/hip_runtime.h>

#define BB   2
#define TT   2048
#define DIN  128
#define NS   64
#define CL   16
#define NC   128     // TT/CL
#define NSUP 16
#define SUPW 8       // NC/NSUP
#define NP   32      // NS/2 packed n-pairs
#define L2E  1.4426950408889634f

typedef float f2_t __attribute__((ext_vector_type(2)));
typedef float f4_t __attribute__((ext_vector_type(4)));

#if __has_builtin(__builtin_amdgcn_exp2f)
__device__ __forceinline__ float fexp2(float x) { return __builtin_amdgcn_exp2f(x); }
#else
__device__ __forceinline__ float fexp2(float x) { return exp2f(x); }
#endif

__device__ __forceinline__ unsigned int f2bfu(float f) {
  unsigned int u = __float_as_uint(f);
  u += 0x7FFFu + ((u >> 16) & 1u);
  return u >> 16;
}
__device__ __forceinline__ unsigned int packbf2(float a, float b) {
  return f2bfu(a) | (f2bfu(b) << 16);
}
__device__ __forceinline__ float bflo(unsigned int u) { return __uint_as_float(u << 16); }
__device__ __forceinline__ float bfhi(unsigned int u) { return __uint_as_float(u & 0xFFFF0000u); }

// ---- K1: xp = x @ W^T ; outputs: xcin, ddx[t][0..127]=delta, BC[t][B|C] ; a2 ----
__global__ __launch_bounds__(128) void k_proj(
    const float* __restrict__ x, const float* __restrict__ W,
    const float* __restrict__ A,
    float* __restrict__ xcin, float* __restrict__ ddx,
    float* __restrict__ BC, float* __restrict__ a2g) {
  __shared__ float xs[128 * 65];
  int tile = blockIdx.x, rg = blockIdx.y, tid = threadIdx.x;
  int base = tile * 128;
  const float4* __restrict__ x4 = (const float4*)(x + (size_t)base * 64);
  for (int i = tid; i < 128 * 16; i += 128) {
    float4 v = x4[i];
    int row = i >> 4, c4 = (i & 15) << 2;
    xs[row * 65 + c4 + 0] = v.x;
    xs[row * 65 + c4 + 1] = v.y;
    xs[row * 65 + c4 + 2] = v.z;
    xs[row * 65 + c4 + 3] = v.w;
  }
  if (tile == 0 && rg == 0 && tid < NS) {
    float s = 0.f;
    const float* __restrict__ Ar = A + tid * NS;
    for (int m = 0; m < NS; ++m) s += Ar[m];
    a2g[tid] = s * L2E;
  }
  __syncthreads();
  float xr[64];
#pragma unroll
  for (int k = 0; k < 64; ++k) xr[k] = xs[tid * 65 + k];
  int bt = base + tid;
#pragma unroll 4
  for (int rr = 0; rr < 16; ++rr) {
    int r = rg * 16 + rr;
    const float* __restrict__ wrow = W + r * 64;
    float a0 = 0.f, a1 = 0.f, a2 = 0.f, a3 = 0.f;
#pragma unroll
    for (int k = 0; k < 64; k += 4) {
      a0 = fmaf(xr[k + 0], wrow[k + 0], a0);
      a1 = fmaf(xr[k + 1], wrow[k + 1], a1);
      a2 = fmaf(xr[k + 2], wrow[k + 2], a2);
      a3 = fmaf(xr[k + 3], wrow[k + 3], a3);
    }
    float acc = (a0 + a1) + (a2 + a3);
    if (r < 128) {
      xcin[(size_t)bt * DIN + r] = acc;
    } else if (r < 256) {
      ddx[(size_t)bt * 256 + (r - 128)] = 1.f / (1.f + fexp2(-acc * L2E));
    } else if (r < 320) {
      BC[(size_t)bt * 128 + (r - 256)] = acc;
    } else {
      BC[(size_t)bt * 128 + 64 + (r - 320)] = acc;
    }
  }
}

// ---- K2: merged fwd+rev local chunk scans; also emits dx & ybase ----
__global__ __launch_bounds__(1024) void k_scan1(
    const float* __restrict__ xcin, float* __restrict__ ddx,
    const float* __restrict__ BC, const float* __restrict__ a2g,
    const float* __restrict__ cw, const float* __restrict__ cb,
    const float* __restrict__ Dp, float* __restrict__ ybase,
    unsigned int* __restrict__ hendP, float* __restrict__ sumd) {
  __shared__ float xcs[(CL + 3) * DIN];  // 9.5 KB
  __shared__ float des[CL * DIN];        // 8 KB
  __shared__ float Bs[CL * NS];          // 4 KB
  int c = blockIdx.x, b = blockIdx.y;
  int tid = threadIdx.x;
  int d = tid & 127;
  int g = __builtin_amdgcn_readfirstlane(tid >> 7);  // 8 n-groups of 8
  int t0 = c * CL;
  {
    const float* __restrict__ xcB = xcin + (size_t)b * TT * DIN;
    for (int i = tid; i < (CL + 3) * 32; i += 1024) {
      int row = i >> 5, c4 = i & 31;
      int t = t0 - 3 + row;
      float4 v = make_float4(0.f, 0.f, 0.f, 0.f);
      if (t >= 0) v = ((const float4*)(xcB + (size_t)t * DIN))[c4];
      ((float4*)xcs)[i] = v;
    }
    if (tid < CL * 32) {
      int row = tid >> 5, c4 = tid & 31;
      ((float4*)des)[tid] =
          ((const float4*)(ddx + (size_t)(b * TT + t0 + row) * 256))[c4];
    }
    if (tid < CL * 16) {
      int row = tid >> 4, c4 = tid & 15;
      ((float4*)Bs)[tid] =
          ((const float4*)(BC + (size_t)(b * TT + t0 + row) * 128))[c4];
    }
  }
  float cw0 = cw[d * 4 + 0], cw1 = cw[d * 4 + 1], cw2 = cw[d * 4 + 2], cw3 = cw[d * 4 + 3];
  float cbd = cb[d];
  float Dd = Dp[d];
  int nb = g * 8;
  f2_t a2p[4];
#pragma unroll
  for (int j = 0; j < 4; ++j) { a2p[j].x = a2g[nb + 2 * j]; a2p[j].y = a2g[nb + 2 * j + 1]; }
  __syncthreads();
  f2_t hf[4], hr[4], Pp[4];
#pragma unroll
  for (int j = 0; j < 4; ++j) {
    hf[j] = (f2_t){0.f, 0.f}; hr[j] = (f2_t){0.f, 0.f}; Pp[j] = (f2_t){1.f, 1.f};
  }
  float sd = 0.f;
  float w0 = xcs[0 * DIN + d], w1 = xcs[1 * DIN + d], w2 = xcs[2 * DIN + d];
  float* __restrict__ dxB = ddx + (size_t)(b * TT + t0) * 256 + 128 + d;
  float* __restrict__ ybB = ybase + (size_t)(b * TT + t0) * DIN + d;
#pragma unroll
  for (int i = 0; i < CL; ++i) {
    float w3 = xcs[(i + 3) * DIN + d];
    float xconv = fmaf(cw0, w0, fmaf(cw1, w1, fmaf(cw2, w2, fmaf(cw3, w3, cbd))));
    float de = des[i * DIN + d];
    sd += de;
    float dxv = de * xconv;
    if (g == 0) {
      dxB[i * 256] = dxv;
      ybB[i * DIN] = Dd * xconv;
    }
    const f2_t* __restrict__ B2 = (const f2_t*)&Bs[i * NS + nb];
#pragma unroll
    for (int j = 0; j < 4; ++j) {
      f2_t b2 = dxv * B2[j];
      f2_t e2;
      e2.x = fexp2(de * a2p[j].x);
      e2.y = fexp2(de * a2p[j].y);
      hf[j] = e2 * hf[j] + b2;     // v_pk_fma_f32
      hr[j] = Pp[j] * b2 + hr[j];  // v_pk_fma_f32
      Pp[j] = Pp[j] * e2;          // v_pk_mul_f32
    }
    w0 = w1; w1 = w2; w2 = w3;
  }
  size_t h0 = (((size_t)(0 * NC + c) * BB + b) * NP + (nb >> 1)) * DIN + d;
  size_t h1 = (((size_t)(1 * NC + c) * BB + b) * NP + (nb >> 1)) * DIN + d;
#pragma unroll
  for (int j = 0; j < 4; ++j) {
    hendP[h0 + (size_t)j * DIN] = packbf2(hf[j].x, hf[j].y);
    hendP[h1 + (size_t)j * DIN] = packbf2(hr[j].x, hr[j].y);
  }
  if (g == 0) sumd[(c * BB + b) * DIN + d] = sd;
}

// ---- K3: fused combine (full-CU grid 256x512):
//      super chains (regs) + 16-super chain (LDS) + Csup fold -> hinP ----
__global__ __launch_bounds__(512) void k_comb(
    const unsigned int* __restrict__ hendP, const float* __restrict__ sumd,
    const float* __restrict__ a2g, unsigned int* __restrict__ hinP) {
  __shared__ float S0[NSUP][64], S1[NSUP][64];     // 8 KB
  __shared__ float sdS[NSUP][64];                  // 4 KB
  __shared__ float C0[NSUP][64], C1[NSUP][64];     // 8 KB
  int bid = blockIdx.x;            // 256 = (b, dir, np, dh)
  int dh = bid & 1;
  int np = (bid >> 1) & 31;
  int dir = (bid >> 6) & 1;
  int b = bid >> 7;
  int tid = threadIdx.x;
  int dl = tid & 63;
  int d = dh * 64 + dl;
  int sl = __builtin_amdgcn_readfirstlane(tid >> 6);   // 0..7
  float a2n0 = a2g[2 * np], a2n1 = a2g[2 * np + 1];
  float hinLo0[2][SUPW], hinLo1[2][SUPW], pfLoc[2][SUPW];
#pragma unroll
  for (int ss = 0; ss < 2; ++ss) {
    int sp = sl + ss * 8;
    float c0 = 0.f, c1 = 0.f, pf = 0.f;
#pragma unroll
    for (int k = 0; k < SUPW; ++k) {
      int cc = sp * SUPW + (dir ? (SUPW - 1 - k) : k);
      float sdv = sumd[(cc * BB + b) * DIN + d];
      unsigned int hv = hendP[(((size_t)(dir * NC + cc) * BB + b) * NP + np) * DIN + d];
      hinLo0[ss][k] = c0; hinLo1[ss][k] = c1; pfLoc[ss][k] = pf;
      float e0 = fexp2(a2n0 * sdv);
      float e1 = fexp2(a2n1 * sdv);
      c0 = fmaf(e0, c0, bflo(hv));
      c1 = fmaf(e1, c1, bfhi(hv));
      pf += sdv;
    }
    S0[sp][dl] = c0; S1[sp][dl] = c1; sdS[sp][dl] = pf;
  }
  __syncthreads();
  if (sl == 0) {
    float c0 = 0.f, c1 = 0.f;
#pragma unroll
    for (int k = 0; k < NSUP; ++k) {
      int sp = dir ? (NSUP - 1 - k) : k;
      C0[sp][dl] = c0; C1[sp][dl] = c1;
      float sv = sdS[sp][dl];
      float e0 = fexp2(a2n0 * sv);
      float e1 = fexp2(a2n1 * sv);
      c0 = fmaf(e0, c0, S0[sp][dl]);
      c1 = fmaf(e1, c1, S1[sp][dl]);
    }
  }
  __syncthreads();
#pragma unroll
  for (int ss = 0; ss < 2; ++ss) {
    int sp = sl + ss * 8;
    float cs0 = C0[sp][dl], cs1 = C1[sp][dl];
#pragma unroll
    for (int k = 0; k < SUPW; ++k) {
      int cc = sp * SUPW + (dir ? (SUPW - 1 - k) : k);
      float pe0 = fexp2(a2n0 * pfLoc[ss][k]);
      float pe1 = fexp2(a2n1 * pfLoc[ss][k]);
      float v0 = fmaf(pe0, cs0, hinLo0[ss][k]);
      float v1 = fmaf(pe1, cs1, hinLo1[ss][k]);
      hinP[(((size_t)(dir * NC + cc) * BB + b) * NP + np) * DIN + d] = packbf2(v0, v1);
    }
  }
}

// ---- K4: both-dir full scans; no conv (dx precomputed); one-base loads ----
__global__ __launch_bounds__(1024) void k_scan2(
    const float* __restrict__ ddx, const float* __restrict__ BC,
    const float* __restrict__ a2g, const float* __restrict__ ybase,
    const unsigned int* __restrict__ hinP,
    float* __restrict__ out) {
  __shared__ float yred[8][CL][DIN];   // 64 KB
  int c = blockIdx.x, b = blockIdx.y;
  int tid = threadIdx.x;
  int d = tid & 127;
  int g = __builtin_amdgcn_readfirstlane(tid >> 7);  // 0..7
  int dir = g >> 2;                                  // groups 0-3 fwd, 4-7 rev
  int nb = (g & 3) * 16;
  f2_t a2p[8];
#pragma unroll
  for (int j = 0; j < 8; ++j) { a2p[j].x = a2g[nb + 2 * j]; a2p[j].y = a2g[nb + 2 * j + 1]; }
  f2_t h2[8];
  size_t hb0 = (((size_t)(dir * NC + c) * BB + b) * NP + (nb >> 1)) * DIN + d;
#pragma unroll
  for (int jp = 0; jp < 8; ++jp) {
    unsigned int u = hinP[hb0 + (size_t)jp * DIN];
    h2[jp].x = bflo(u);
    h2[jp].y = bfhi(u);
  }
  int t0 = c * CL;
  const float* __restrict__ ddB = ddx + (size_t)(b * TT + t0) * 256 + d;
  const float* __restrict__ BCB = BC + (size_t)(b * TT + t0) * 128 + nb;
  if (dir == 0) {
#pragma unroll
    for (int i = 0; i < CL; ++i) {
      float de  = ddB[i * 256];
      float dxv = ddB[i * 256 + 128];
      f2_t y2 = (f2_t){0.f, 0.f};
#pragma unroll
      for (int jq = 0; jq < 4; ++jq) {
        f4_t bq = *(const f4_t*)&BCB[i * 128 + jq * 4];
        f4_t cq = *(const f4_t*)&BCB[i * 128 + 64 + jq * 4];
        f2_t blo = __builtin_shufflevector(bq, bq, 0, 1);
        f2_t bhi = __builtin_shufflevector(bq, bq, 2, 3);
        f2_t clo = __builtin_shufflevector(cq, cq, 0, 1);
        f2_t chi = __builtin_shufflevector(cq, cq, 2, 3);
        int jp = 2 * jq;
        f2_t e2;
        e2.x = fexp2(de * a2p[jp].x);
        e2.y = fexp2(de * a2p[jp].y);
        h2[jp] = e2 * h2[jp] + dxv * blo;
        y2 = h2[jp] * clo + y2;
        f2_t e3;
        e3.x = fexp2(de * a2p[jp + 1].x);
        e3.y = fexp2(de * a2p[jp + 1].y);
        h2[jp + 1] = e3 * h2[jp + 1] + dxv * bhi;
        y2 = h2[jp + 1] * chi + y2;
      }
      yred[g][i][d] = y2.x + y2.y;
    }
  } else {
#pragma unroll
    for (int i = 0; i < CL; ++i) {
      int ti = CL - 1 - i;
      float de  = ddB[ti * 256];
      float dxv = ddB[ti * 256 + 128];
      f2_t y2 = (f2_t){0.f, 0.f};
#pragma unroll
      for (int jq = 0; jq < 4; ++jq) {
        f4_t bq = *(const f4_t*)&BCB[ti * 128 + jq * 4];
        f4_t cq = *(const f4_t*)&BCB[ti * 128 + 64 + jq * 4];
        f2_t blo = __builtin_shufflevector(bq, bq, 0, 1);
        f2_t bhi = __builtin_shufflevector(bq, bq, 2, 3);
        f2_t clo = __builtin_shufflevector(cq, cq, 0, 1);
        f2_t chi = __builtin_shufflevector(cq, cq, 2, 3);
        int jp = 2 * jq;
        f2_t e2;
        e2.x = fexp2(de * a2p[jp].x);
        e2.y = fexp2(de * a2p[jp].y);
        h2[jp] = e2 * h2[jp] + dxv * blo;
        y2 = h2[jp] * clo + y2;
        f2_t e3;
        e3.x = fexp2(de * a2p[jp + 1].x);
        e3.y = fexp2(de * a2p[jp + 1].y);
        h2[jp + 1] = e3 * h2[jp + 1] + dxv * bhi;
        y2 = h2[jp + 1] * chi + y2;
      }
      yred[g][i][d] = y2.x + y2.y;
    }
  }
  __syncthreads();
#pragma unroll
  for (int k = 0; k < 2; ++k) {
    int p = k * 1024 + tid;
    int i = p >> 7, d2 = p & 127;
    int ir = CL - 1 - i;
    float sf = (yred[0][i][d2] + yred[1][i][d2]) + (yred[2][i][d2] + yred[3][i][d2]);
    float sr = (yred[4][ir][d2] + yred[5][ir][d2]) + (yred[6][ir][d2] + yred[7][ir][d2]);
    size_t oidx = ((size_t)b * TT + t0 + i) * DIN + d2;
    out[oidx] = sf + sr + ybase[oidx];
  }
}

extern "C" void kernel_launch(void* const* d_in, const int* in_sizes, int n_in,
                              void* d_out, int out_size, void* d_ws, size_t ws_size,
                              hipStream_t stream) {
  const float* x  = (const float*)d_in[0];
  const float* W  = (const float*)d_in[1];
  const float* cw = (const float*)d_in[2];
  const float* cb = (const float*)d_in[3];
  const float* A  = (const float*)d_in[4];
  const float* Dp = (const float*)d_in[5];
  float* out = (float*)d_out;

  float* ws = (float*)d_ws;
  float* xcin   = ws;                      // 524288
  float* ddx    = xcin + 524288;           // 1048576 (delta | dx interleaved)
  float* BCbuf  = ddx + 1048576;           // 524288  (B | C interleaved)
  float* ybase  = BCbuf + 524288;          // 524288
  float* a2g    = ybase + 524288;          // 128
  float* sumd   = a2g + 128;               // 32768
  unsigned int* hendP = (unsigned int*)(sumd + 32768);   // 2097152 uints
  unsigned int* hinP  = hendP + 2097152;                 // 2097152 uints
  // total ~27 MB

  hipLaunchKernelGGL(k_proj,  dim3(32, 24), dim3(128), 0, stream,
                     x, W, A, xcin, ddx, BCbuf, a2g);
  hipLaunchKernelGGL(k_scan1, dim3(NC, BB), dim3(1024), 0, stream,
                     xcin, ddx, BCbuf, a2g, cw, cb, Dp, ybase, hendP, sumd);
  hipLaunchKernelGGL(k_comb,  dim3(256), dim3(512), 0, stream,
                     hendP, sumd, a2g, hinP);
  hipLaunchKernelGGL(k_scan2, dim3(NC, BB), dim3(1024), 0, stream,
                     ddx, BCbuf, a2g, ybase, hinP, out);
}

// Round 19
// 56.829 us; speedup vs baseline: 2.0978x; 1.1399x over previous
//
#include <hip/hip_runtime.h>

#define BB   2
#define TT   2048
#define DIN  128
#define NS   64
#define CL   16
#define NC   128     // TT/CL
#define NSUP 16
#define SUPW 8       // NC/NSUP
#define NP   32      // NS/2 packed n-pairs
#define L2E  1.4426950408889634f

typedef float f2_t __attribute__((ext_vector_type(2)));
typedef float f4_t __attribute__((ext_vector_type(4)));

#if __has_builtin(__builtin_amdgcn_exp2f)
__device__ __forceinline__ float fexp2(float x) { return __builtin_amdgcn_exp2f(x); }
#else
__device__ __forceinline__ float fexp2(float x) { return exp2f(x); }
#endif

__device__ __forceinline__ unsigned int f2bfu(float f) {
  unsigned int u = __float_as_uint(f);
  u += 0x7FFFu + ((u >> 16) & 1u);
  return u >> 16;
}
__device__ __forceinline__ unsigned int packbf2(float a, float b) {
  return f2bfu(a) | (f2bfu(b) << 16);
}
__device__ __forceinline__ float bflo(unsigned int u) { return __uint_as_float(u << 16); }
__device__ __forceinline__ float bfhi(unsigned int u) { return __uint_as_float(u & 0xFFFF0000u); }

// ---- K1: xp = x @ W^T ; split into xcin / delta(sigmoid) / B / C ; a2 ----
__global__ __launch_bounds__(128) void k_proj(
    const float* __restrict__ x, const float* __restrict__ W,
    const float* __restrict__ A,
    float* __restrict__ xcin, float* __restrict__ delta,
    float* __restrict__ Bb, float* __restrict__ Cb, float* __restrict__ a2g) {
  __shared__ float xs[128 * 65];
  int tile = blockIdx.x, rg = blockIdx.y, tid = threadIdx.x;
  int base = tile * 128;
  const float4* __restrict__ x4 = (const float4*)(x + (size_t)base * 64);
  for (int i = tid; i < 128 * 16; i += 128) {
    float4 v = x4[i];
    int row = i >> 4, c4 = (i & 15) << 2;
    xs[row * 65 + c4 + 0] = v.x;
    xs[row * 65 + c4 + 1] = v.y;
    xs[row * 65 + c4 + 2] = v.z;
    xs[row * 65 + c4 + 3] = v.w;
  }
  if (tile == 0 && rg == 0 && tid < NS) {
    float s = 0.f;
    const float* __restrict__ Ar = A + tid * NS;
    for (int m = 0; m < NS; ++m) s += Ar[m];
    a2g[tid] = s * L2E;
  }
  __syncthreads();
  float xr[64];
#pragma unroll
  for (int k = 0; k < 64; ++k) xr[k] = xs[tid * 65 + k];
  int bt = base + tid;
#pragma unroll 4
  for (int rr = 0; rr < 16; ++rr) {
    int r = rg * 16 + rr;
    const float* __restrict__ wrow = W + r * 64;
    float a0 = 0.f, a1 = 0.f, a2 = 0.f, a3 = 0.f;
#pragma unroll
    for (int k = 0; k < 64; k += 4) {
      a0 = fmaf(xr[k + 0], wrow[k + 0], a0);
      a1 = fmaf(xr[k + 1], wrow[k + 1], a1);
      a2 = fmaf(xr[k + 2], wrow[k + 2], a2);
      a3 = fmaf(xr[k + 3], wrow[k + 3], a3);
    }
    float acc = (a0 + a1) + (a2 + a3);
    if (r < 128) {
      xcin[(size_t)bt * DIN + r] = acc;
    } else if (r < 256) {
      delta[(size_t)bt * DIN + (r - 128)] = 1.f / (1.f + fexp2(-acc * L2E));
    } else if (r < 320) {
      Bb[(size_t)bt * NS + (r - 256)] = acc;
    } else {
      Cb[(size_t)bt * NS + (r - 320)] = acc;
    }
  }
}

// ---- K2: merged fwd+rev local chunk scans (shared exp), LDS-staged, pk f32 ----
__global__ __launch_bounds__(1024) void k_scan1(
    const float* __restrict__ xcin, const float* __restrict__ delta,
    const float* __restrict__ Bb, const float* __restrict__ a2g,
    const float* __restrict__ cw, const float* __restrict__ cb,
    unsigned int* __restrict__ hendP, float* __restrict__ sumd) {
  __shared__ float xcs[(CL + 3) * DIN];  // 9.5 KB
  __shared__ float des[CL * DIN];        // 8 KB
  __shared__ float Bs[CL * NS];          // 4 KB
  int c = blockIdx.x, b = blockIdx.y;
  int tid = threadIdx.x;
  int d = tid & 127;
  int g = __builtin_amdgcn_readfirstlane(tid >> 7);  // 8 n-groups of 8
  int t0 = c * CL;
  {
    const float* __restrict__ xcB = xcin + (size_t)b * TT * DIN;
    for (int i = tid; i < (CL + 3) * 32; i += 1024) {
      int row = i >> 5, c4 = i & 31;
      int t = t0 - 3 + row;
      float4 v = make_float4(0.f, 0.f, 0.f, 0.f);
      if (t >= 0) v = ((const float4*)(xcB + (size_t)t * DIN))[c4];
      ((float4*)xcs)[i] = v;
    }
    if (tid < CL * 32)
      ((float4*)des)[tid] = ((const float4*)(delta + (size_t)(b * TT + t0) * DIN))[tid];
    if (tid < CL * 16)
      ((float4*)Bs)[tid] = ((const float4*)(Bb + (size_t)(b * TT + t0) * NS))[tid];
  }
  float cw0 = cw[d * 4 + 0], cw1 = cw[d * 4 + 1], cw2 = cw[d * 4 + 2], cw3 = cw[d * 4 + 3];
  float cbd = cb[d];
  int nb = g * 8;
  f2_t a2p[4];
#pragma unroll
  for (int j = 0; j < 4; ++j) { a2p[j].x = a2g[nb + 2 * j]; a2p[j].y = a2g[nb + 2 * j + 1]; }
  __syncthreads();
  f2_t hf[4], hr[4], Pp[4];
#pragma unroll
  for (int j = 0; j < 4; ++j) {
    hf[j] = (f2_t){0.f, 0.f}; hr[j] = (f2_t){0.f, 0.f}; Pp[j] = (f2_t){1.f, 1.f};
  }
  float sd = 0.f;
  float w0 = xcs[0 * DIN + d], w1 = xcs[1 * DIN + d], w2 = xcs[2 * DIN + d];
#pragma unroll
  for (int i = 0; i < CL; ++i) {
    float w3 = xcs[(i + 3) * DIN + d];
    float xconv = fmaf(cw0, w0, fmaf(cw1, w1, fmaf(cw2, w2, fmaf(cw3, w3, cbd))));
    float de = des[i * DIN + d];
    sd += de;
    float dxv = de * xconv;
    const f2_t* __restrict__ B2 = (const f2_t*)&Bs[i * NS + nb];
#pragma unroll
    for (int j = 0; j < 4; ++j) {
      f2_t b2 = dxv * B2[j];
      f2_t e2;
      e2.x = fexp2(de * a2p[j].x);
      e2.y = fexp2(de * a2p[j].y);
      hf[j] = e2 * hf[j] + b2;     // v_pk_fma_f32
      hr[j] = Pp[j] * b2 + hr[j];  // v_pk_fma_f32
      Pp[j] = Pp[j] * e2;          // v_pk_mul_f32
    }
    w0 = w1; w1 = w2; w2 = w3;
  }
  size_t h0 = (((size_t)(0 * NC + c) * BB + b) * NP + (nb >> 1)) * DIN + d;
  size_t h1 = (((size_t)(1 * NC + c) * BB + b) * NP + (nb >> 1)) * DIN + d;
#pragma unroll
  for (int j = 0; j < 4; ++j) {
    hendP[h0 + (size_t)j * DIN] = packbf2(hf[j].x, hf[j].y);
    hendP[h1 + (size_t)j * DIN] = packbf2(hr[j].x, hr[j].y);
  }
  if (g == 0) sumd[(c * BB + b) * DIN + d] = sd;
}

// ---- K3: fused combine (full-CU grid 256x512):
//      super chains (regs) + 16-super chain (LDS) + Csup fold -> hinP ----
__global__ __launch_bounds__(512) void k_comb(
    const unsigned int* __restrict__ hendP, const float* __restrict__ sumd,
    const float* __restrict__ a2g, unsigned int* __restrict__ hinP) {
  __shared__ float S0[NSUP][64], S1[NSUP][64];     // 8 KB
  __shared__ float sdS[NSUP][64];                  // 4 KB
  __shared__ float C0[NSUP][64], C1[NSUP][64];     // 8 KB
  int bid = blockIdx.x;            // 256 = (b, dir, np, dh)
  int dh = bid & 1;
  int np = (bid >> 1) & 31;
  int dir = (bid >> 6) & 1;
  int b = bid >> 7;
  int tid = threadIdx.x;
  int dl = tid & 63;
  int d = dh * 64 + dl;
  int sl = __builtin_amdgcn_readfirstlane(tid >> 6);   // 0..7
  float a2n0 = a2g[2 * np], a2n1 = a2g[2 * np + 1];
  float hinLo0[2][SUPW], hinLo1[2][SUPW], pfLoc[2][SUPW];
#pragma unroll
  for (int ss = 0; ss < 2; ++ss) {
    int sp = sl + ss * 8;
    float c0 = 0.f, c1 = 0.f, pf = 0.f;
#pragma unroll
    for (int k = 0; k < SUPW; ++k) {
      int cc = sp * SUPW + (dir ? (SUPW - 1 - k) : k);
      float sdv = sumd[(cc * BB + b) * DIN + d];
      unsigned int hv = hendP[(((size_t)(dir * NC + cc) * BB + b) * NP + np) * DIN + d];
      hinLo0[ss][k] = c0; hinLo1[ss][k] = c1; pfLoc[ss][k] = pf;
      float e0 = fexp2(a2n0 * sdv);
      float e1 = fexp2(a2n1 * sdv);
      c0 = fmaf(e0, c0, bflo(hv));
      c1 = fmaf(e1, c1, bfhi(hv));
      pf += sdv;
    }
    S0[sp][dl] = c0; S1[sp][dl] = c1; sdS[sp][dl] = pf;
  }
  __syncthreads();
  if (sl == 0) {
    float c0 = 0.f, c1 = 0.f;
#pragma unroll
    for (int k = 0; k < NSUP; ++k) {
      int sp = dir ? (NSUP - 1 - k) : k;
      C0[sp][dl] = c0; C1[sp][dl] = c1;
      float sv = sdS[sp][dl];
      float e0 = fexp2(a2n0 * sv);
      float e1 = fexp2(a2n1 * sv);
      c0 = fmaf(e0, c0, S0[sp][dl]);
      c1 = fmaf(e1, c1, S1[sp][dl]);
    }
  }
  __syncthreads();
#pragma unroll
  for (int ss = 0; ss < 2; ++ss) {
    int sp = sl + ss * 8;
    float cs0 = C0[sp][dl], cs1 = C1[sp][dl];
#pragma unroll
    for (int k = 0; k < SUPW; ++k) {
      int cc = sp * SUPW + (dir ? (SUPW - 1 - k) : k);
      float pe0 = fexp2(a2n0 * pfLoc[ss][k]);
      float pe1 = fexp2(a2n1 * pfLoc[ss][k]);
      float v0 = fmaf(pe0, cs0, hinLo0[ss][k]);
      float v1 = fmaf(pe1, cs1, hinLo1[ss][k]);
      hinP[(((size_t)(dir * NC + cc) * BB + b) * NP + np) * DIN + d] = packbf2(v0, v1);
    }
  }
}

// ---- K4: both-direction full scans; init = hinP only; pk f32; LDS reduce ----
__global__ __launch_bounds__(1024) void k_scan2(
    const float* __restrict__ xcin, const float* __restrict__ delta,
    const float* __restrict__ Bb, const float* __restrict__ Cb,
    const float* __restrict__ a2g, const float* __restrict__ cw,
    const float* __restrict__ cb, const float* __restrict__ Dp,
    const unsigned int* __restrict__ hinP,
    float* __restrict__ out) {
  __shared__ float yred[8][CL][DIN];   // 64 KB
  int c = blockIdx.x, b = blockIdx.y;
  int tid = threadIdx.x;
  int d = tid & 127;
  int g = __builtin_amdgcn_readfirstlane(tid >> 7);  // 0..7
  int dir = g >> 2;                                  // groups 0-3 fwd, 4-7 rev
  int nb = (g & 3) * 16;
  float cw0 = cw[d * 4 + 0], cw1 = cw[d * 4 + 1], cw2 = cw[d * 4 + 2], cw3 = cw[d * 4 + 3];
  float cbd = cb[d];
  float Dd = Dp[d];
  f2_t a2p[8];
#pragma unroll
  for (int j = 0; j < 8; ++j) { a2p[j].x = a2g[nb + 2 * j]; a2p[j].y = a2g[nb + 2 * j + 1]; }
  f2_t h2[8];
  size_t hb0 = (((size_t)(dir * NC + c) * BB + b) * NP + (nb >> 1)) * DIN + d;
#pragma unroll
  for (int jp = 0; jp < 8; ++jp) {
    unsigned int u = hinP[hb0 + (size_t)jp * DIN];
    h2[jp].x = bflo(u);
    h2[jp].y = bfhi(u);
  }
  int t0 = c * CL;
  const float* __restrict__ xcB = xcin + (size_t)b * TT * DIN + d;
  const float* __restrict__ deB = delta + (size_t)b * TT * DIN + d;
  const float* __restrict__ BbB = Bb + (size_t)b * TT * NS + nb;
  const float* __restrict__ CbB = Cb + (size_t)b * TT * NS + nb;
  bool addD = (g == 0);
  float w0, w1, w2, w3;
  if (dir == 0) {
    int t = t0;
    w0 = (t - 3 >= 0) ? xcB[(t - 3) * DIN] : 0.f;
    w1 = (t - 2 >= 0) ? xcB[(t - 2) * DIN] : 0.f;
    w2 = (t - 1 >= 0) ? xcB[(t - 1) * DIN] : 0.f;
    w3 = xcB[t * DIN];
#pragma unroll
    for (int i = 0; i < CL; ++i) {
      float xconv = fmaf(cw0, w0, fmaf(cw1, w1, fmaf(cw2, w2, fmaf(cw3, w3, cbd))));
      float de = deB[t * DIN];
      float dxv = de * xconv;
      f2_t y2 = (f2_t){0.f, 0.f};
#pragma unroll
      for (int jq = 0; jq < 4; ++jq) {
        f4_t bq = *(const f4_t*)&BbB[t * NS + jq * 4];
        f4_t cq = *(const f4_t*)&CbB[t * NS + jq * 4];
        f2_t blo = __builtin_shufflevector(bq, bq, 0, 1);
        f2_t bhi = __builtin_shufflevector(bq, bq, 2, 3);
        f2_t clo = __builtin_shufflevector(cq, cq, 0, 1);
        f2_t chi = __builtin_shufflevector(cq, cq, 2, 3);
        int jp = 2 * jq;
        f2_t e2;
        e2.x = fexp2(de * a2p[jp].x);
        e2.y = fexp2(de * a2p[jp].y);
        h2[jp] = e2 * h2[jp] + dxv * blo;
        y2 = h2[jp] * clo + y2;
        f2_t e3;
        e3.x = fexp2(de * a2p[jp + 1].x);
        e3.y = fexp2(de * a2p[jp + 1].y);
        h2[jp + 1] = e3 * h2[jp + 1] + dxv * bhi;
        y2 = h2[jp + 1] * chi + y2;
      }
      float yv = y2.x + y2.y;
      if (addD) yv = fmaf(Dd, xconv, yv);
      yred[g][i][d] = yv;
      if (i < CL - 1) { ++t; w0 = w1; w1 = w2; w2 = w3; w3 = xcB[t * DIN]; }
    }
  } else {
    int t = t0 + CL - 1;
    w3 = xcB[t * DIN];
    w2 = xcB[(t - 1) * DIN];
    w1 = xcB[(t - 2) * DIN];
    w0 = xcB[(t - 3) * DIN];
#pragma unroll
    for (int i = 0; i < CL; ++i) {
      float xconv = fmaf(cw0, w0, fmaf(cw1, w1, fmaf(cw2, w2, fmaf(cw3, w3, cbd))));
      float de = deB[t * DIN];
      float dxv = de * xconv;
      f2_t y2 = (f2_t){0.f, 0.f};
#pragma unroll
      for (int jq = 0; jq < 4; ++jq) {
        f4_t bq = *(const f4_t*)&BbB[t * NS + jq * 4];
        f4_t cq = *(const f4_t*)&CbB[t * NS + jq * 4];
        f2_t blo = __builtin_shufflevector(bq, bq, 0, 1);
        f2_t bhi = __builtin_shufflevector(bq, bq, 2, 3);
        f2_t clo = __builtin_shufflevector(cq, cq, 0, 1);
        f2_t chi = __builtin_shufflevector(cq, cq, 2, 3);
        int jp = 2 * jq;
        f2_t e2;
        e2.x = fexp2(de * a2p[jp].x);
        e2.y = fexp2(de * a2p[jp].y);
        h2[jp] = e2 * h2[jp] + dxv * blo;
        y2 = h2[jp] * clo + y2;
        f2_t e3;
        e3.x = fexp2(de * a2p[jp + 1].x);
        e3.y = fexp2(de * a2p[jp + 1].y);
        h2[jp + 1] = e3 * h2[jp + 1] + dxv * bhi;
        y2 = h2[jp + 1] * chi + y2;
      }
      // store time-flipped so the reduce needs no re-index
      yred[g][CL - 1 - i][d] = y2.x + y2.y;
      if (i < CL - 1) { --t; w3 = w2; w2 = w1; w1 = w0; w0 = (t - 3 >= 0) ? xcB[(t - 3) * DIN] : 0.f; }
    }
  }
  __syncthreads();
#pragma unroll
  for (int k = 0; k < 2; ++k) {
    int p = k * 1024 + tid;
    int i = p >> 7, d2 = p & 127;
    float sf = (yred[0][i][d2] + yred[1][i][d2]) + (yred[2][i][d2] + yred[3][i][d2]);
    float sr = (yred[4][i][d2] + yred[5][i][d2]) + (yred[6][i][d2] + yred[7][i][d2]);
    out[((size_t)b * TT + t0 + i) * DIN + d2] = sf + sr;
  }
}

extern "C" void kernel_launch(void* const* d_in, const int* in_sizes, int n_in,
                              void* d_out, int out_size, void* d_ws, size_t ws_size,
                              hipStream_t stream) {
  const float* x  = (const float*)d_in[0];
  const float* W  = (const float*)d_in[1];
  const float* cw = (const float*)d_in[2];
  const float* cb = (const float*)d_in[3];
  const float* A  = (const float*)d_in[4];
  const float* Dp = (const float*)d_in[5];
  float* out = (float*)d_out;

  float* ws = (float*)d_ws;
  float* xcin   = ws;                      // 524288
  float* delta  = xcin + 524288;           // 524288
  float* Bbuf   = delta + 524288;          // 262144
  float* Cbuf   = Bbuf + 262144;           // 262144
  float* a2g    = Cbuf + 262144;           // 128
  float* sumd   = a2g + 128;               // 32768
  unsigned int* hendP = (unsigned int*)(sumd + 32768);   // 2097152 uints
  unsigned int* hinP  = hendP + 2097152;                 // 2097152 uints
  // total ~23 MB

  hipLaunchKernelGGL(k_proj,  dim3(32, 24), dim3(128), 0, stream,
                     x, W, A, xcin, delta, Bbuf, Cbuf, a2g);
  hipLaunchKernelGGL(k_scan1, dim3(NC, BB), dim3(1024), 0, stream,
                     xcin, delta, Bbuf, a2g, cw, cb, hendP, sumd);
  hipLaunchKernelGGL(k_comb,  dim3(256), dim3(512), 0, stream,
                     hendP, sumd, a2g, hinP);
  hipLaunchKernelGGL(k_scan2, dim3(NC, BB), dim3(1024), 0, stream,
                     xcin, delta, Bbuf, Cbuf, a2g, cw, cb, Dp, hinP, out);
}